// Round 6
// baseline (170.370 us; speedup 1.0000x reference)
//
#include <hip/hip_runtime.h>

#define NB 65536
#define NN 128
#define FDIM 16
#define ODIM 64
#define REP 32   // in-dispatch replication factor (measurement round)

typedef __attribute__((ext_vector_type(8))) short s16x8;
typedef __attribute__((ext_vector_type(4))) float f32x4;
typedef __attribute__((address_space(3))) void lds_void_t;
typedef const __attribute__((address_space(1))) void gbl_void_t;

__device__ __forceinline__ unsigned short f2bf_rne(float f) {
    unsigned u = __builtin_bit_cast(unsigned, f);
    u += 0x7FFFu + ((u >> 16) & 1u);
    return (unsigned short)(u >> 16);
}

// ---------------------------------------------------------------------------
// Kernel 1: W' = 0.5*S (symmetric, zero diag), bf16 B-fragment layout.
// 512 blocks x 256 threads, 8 lanes per length-64 dot. (unchanged from r4/r5)
// ---------------------------------------------------------------------------
__global__ __launch_bounds__(256) void prep_w_fast(const float* __restrict__ kern,
                                                   const int* __restrict__ fd,
                                                   unsigned short* __restrict__ wfrag) {
    int d = blockIdx.x * 32 + (threadIdx.x >> 3);  // entry: i=K idx, j=N idx
    int i = d >> 7, j = d & 127;
    int part = threadIdx.x & 7;
    int fi = fd[i], fj = fd[j];
    const float4* ap = (const float4*)(kern + (i * FDIM + fj) * ODIM + part * 8);
    const float4* bp = (const float4*)(kern + (j * FDIM + fi) * ODIM + part * 8);
    float4 a0 = ap[0], a1 = ap[1];
    float4 b0 = bp[0], b1 = bp[1];
    float s = a0.x * b0.x + a0.y * b0.y + a0.z * b0.z + a0.w * b0.w +
              a1.x * b1.x + a1.y * b1.y + a1.z * b1.z + a1.w * b1.w;
    s += __shfl_xor(s, 1, 64);
    s += __shfl_xor(s, 2, 64);
    s += __shfl_xor(s, 4, 64);
    if (part == 0) {
        float w = (i == j) ? 0.f : 0.5f * s;
        int kt = i >> 5, kc = (i >> 3) & 3, e = i & 7;
        wfrag[(((j >> 4) * 4 + kt) * 64 + kc * 16 + (j & 15)) * 8 + e] = f2bf_rne(w);
    }
}

// ---------------------------------------------------------------------------
// Kernel 2 (MEASUREMENT ROUND): byte-identical algorithm to round 5, but the
// grid is replicated REP x (bid = blockIdx.x & 511). 32 blocks redundantly
// compute and store IDENTICAL bytes to the same out locations (deterministic;
// duplicate same-value stores are race-benign). Purpose: push this dispatch
// past the 40 us harness fills into rocprof's top-5 so we finally see its
// counters, and measure t_qform = (dur - floor)/REP.
// ---------------------------------------------------------------------------
__global__ __launch_bounds__(256, 4) void qform_rep(const float* __restrict__ x,
                                                    const unsigned short* __restrict__ wfrag,
                                                    float* __restrict__ out) {
    __shared__ __align__(16) unsigned short wlds[16384];  // 32 KB

    const int tid = threadIdx.x;
    const int bid = blockIdx.x & 511;   // 32-fold replication of the 512-block job

    // async W stage: 32 KB, linear layout, direct-to-LDS
    {
        const char* gsrc = (const char*)wfrag;
        char* ldst = (char*)wlds;
#pragma unroll
        for (int t = 0; t < 8; ++t) {
            int off = t * 4096 + tid * 16;
            __builtin_amdgcn_global_load_lds((gbl_void_t*)(gsrc + off),
                                             (lds_void_t*)(ldst + off), 16, 0, 0);
        }
    }

    const int wave = tid >> 6, lane = tid & 63;
    const int row = lane & 15, kc = lane >> 4;
    const int t0 = wave * 2, t1 = t0 + 1;
    const size_t base = (size_t)bid * 128;
    const float* xp0 = x + (base + (size_t)(t0 * 16 + row)) * NN + kc * 8;
    const float* xp1 = x + (base + (size_t)(t1 * 16 + row)) * NN + kc * 8;

    s16x8 ah0[4], ah1[4];
#pragma unroll
    for (int kt = 0; kt < 4; ++kt) {
        const float4* p0 = (const float4*)(xp0 + kt * 32);
        const float4* p1 = (const float4*)(xp1 + kt * 32);
        float4 v00 = p0[0], v01 = p0[1], v10 = p1[0], v11 = p1[1];
        float vs0[8] = {v00.x, v00.y, v00.z, v00.w, v01.x, v01.y, v01.z, v01.w};
        float vs1[8] = {v10.x, v10.y, v10.z, v10.w, v11.x, v11.y, v11.z, v11.w};
#pragma unroll
        for (int e = 0; e < 8; ++e) {
            ah0[kt][e] = (short)f2bf_rne(vs0[e]);
            ah1[kt][e] = (short)f2bf_rne(vs1[e]);
        }
    }
    __syncthreads();  // drains vmcnt (W stage)

    const int rg = lane >> 4, cl = lane & 15;
    const float* e0 = x + (base + (size_t)(t0 * 16 + rg * 4)) * NN + cl;
    const float* e1 = x + (base + (size_t)(t1 * 16 + rg * 4)) * NN + cl;

    float q00 = 0, q01 = 0, q02 = 0, q03 = 0;
    float q10 = 0, q11 = 0, q12 = 0, q13 = 0;
#pragma unroll
    for (int nt = 0; nt < 8; ++nt) {
        f32x4 c0 = {0.f, 0.f, 0.f, 0.f}, c1 = {0.f, 0.f, 0.f, 0.f};
#pragma unroll
        for (int kt = 0; kt < 4; ++kt) {
            s16x8 bf = *(const s16x8*)&wlds[((nt * 4 + kt) * 64 + lane) * 8];
            c0 = __builtin_amdgcn_mfma_f32_16x16x32_bf16(ah0[kt], bf, c0, 0, 0, 0);
            c1 = __builtin_amdgcn_mfma_f32_16x16x32_bf16(ah1[kt], bf, c1, 0, 0, 0);
        }
        // D layout (m89-verified): col = lane&15, row = (lane>>4)*4 + reg
        const int nc = nt * 16;
        q00 += c0[0] * e0[0 * NN + nc];
        q01 += c0[1] * e0[1 * NN + nc];
        q02 += c0[2] * e0[2 * NN + nc];
        q03 += c0[3] * e0[3 * NN + nc];
        q10 += c1[0] * e1[0 * NN + nc];
        q11 += c1[1] * e1[1 * NN + nc];
        q12 += c1[2] * e1[2 * NN + nc];
        q13 += c1[3] * e1[3 * NN + nc];
    }
#pragma unroll
    for (int m = 1; m <= 8; m <<= 1) {
        q00 += __shfl_xor(q00, m, 64); q01 += __shfl_xor(q01, m, 64);
        q02 += __shfl_xor(q02, m, 64); q03 += __shfl_xor(q03, m, 64);
        q10 += __shfl_xor(q10, m, 64); q11 += __shfl_xor(q11, m, 64);
        q12 += __shfl_xor(q12, m, 64); q13 += __shfl_xor(q13, m, 64);
    }
    if (cl == 0) {
        float4 o0 = {q00, q01, q02, q03};
        float4 o1 = {q10, q11, q12, q13};
        *(float4*)(out + base + t0 * 16 + rg * 4) = o0;
        *(float4*)(out + base + t1 * 16 + rg * 4) = o1;
    }
}

extern "C" void kernel_launch(void* const* d_in, const int* in_sizes, int n_in,
                              void* d_out, int out_size, void* d_ws, size_t ws_size,
                              hipStream_t stream) {
    const float* x = (const float*)d_in[0];
    const float* kern = (const float*)d_in[1];
    const int* fd = (const int*)d_in[2];
    float* out = (float*)d_out;
    unsigned short* wfrag = (unsigned short*)d_ws;  // 32 KB used

    prep_w_fast<<<dim3(512), dim3(256), 0, stream>>>(kern, fd, wfrag);
    qform_rep<<<dim3(512 * REP), dim3(256), 0, stream>>>(x, wfrag, out);
}

// Round 7
// 21.702 us; speedup vs baseline: 7.8505x; 7.8505x over previous
//
#include <hip/hip_runtime.h>

#define NB 65536
#define NN 128
#define FDIM 16
#define ODIM 64

typedef __attribute__((ext_vector_type(8))) short s16x8;
typedef __attribute__((ext_vector_type(4))) float f32x4;

__device__ __forceinline__ unsigned short f2bf_rne(float f) {
    unsigned u = __builtin_bit_cast(unsigned, f);
    u += 0x7FFFu + ((u >> 16) & 1u);
    return (unsigned short)(u >> 16);
}

// ---------------------------------------------------------------------------
// Kernel 1: W' = 0.5*S (symmetric, zero diag), bf16 B-fragment layout.
// 512 blocks x 256 threads, 8 lanes per length-64 dot. (validated r3-r6)
// ---------------------------------------------------------------------------
__global__ __launch_bounds__(256) void prep_w_fast(const float* __restrict__ kern,
                                                   const int* __restrict__ fd,
                                                   unsigned short* __restrict__ wfrag) {
    int d = blockIdx.x * 32 + (threadIdx.x >> 3);  // entry: i=K idx, j=N idx
    int i = d >> 7, j = d & 127;
    int part = threadIdx.x & 7;
    int fi = fd[i], fj = fd[j];
    const float4* ap = (const float4*)(kern + (i * FDIM + fj) * ODIM + part * 8);
    const float4* bp = (const float4*)(kern + (j * FDIM + fi) * ODIM + part * 8);
    float4 a0 = ap[0], a1 = ap[1];
    float4 b0 = bp[0], b1 = bp[1];
    float s = a0.x * b0.x + a0.y * b0.y + a0.z * b0.z + a0.w * b0.w +
              a1.x * b1.x + a1.y * b1.y + a1.z * b1.z + a1.w * b1.w;
    s += __shfl_xor(s, 1, 64);
    s += __shfl_xor(s, 2, 64);
    s += __shfl_xor(s, 4, 64);
    if (part == 0) {
        float w = (i == j) ? 0.f : 0.5f * s;
        int kt = i >> 5, kc = (i >> 3) & 3, e = i & 7;
        wfrag[(((j >> 4) * 4 + kt) * 64 + kc * 16 + (j & 15)) * 8 + e] = f2bf_rne(w);
    }
}

// ---------------------------------------------------------------------------
// Kernel 2: out[b] = x_b^T W' x_b.  Occupancy-focused final variant:
//  - NO LDS, NO barrier: W B-frags read per-wave straight from global
//    (wfrag = 32 KB, L2-resident on every XCD; 64 MB aggregate L2 traffic
//    ~1.9 us at 34.5 TB/s, overlaps the x HBM/L3 stream)
//  - __launch_bounds__(256,6): target ~24 waves/CU (was ~16 + barrier)
//  - #pragma unroll 2 on nt-loop bounds W-load hoisting (<=8 loads in
//    flight, ~84 VGPR, no scratch)
// 512 blocks x 256 thr (4 waves), 2 tiles/wave; epilogue re-reads x fp32
// from global (L1/L2-hot; validated equal to LDS staging in r5).
// ---------------------------------------------------------------------------
__global__ __launch_bounds__(256, 6) void qform_nolds(const float* __restrict__ x,
                                                      const unsigned short* __restrict__ wfrag,
                                                      float* __restrict__ out) {
    const int tid = threadIdx.x;
    const int bid = blockIdx.x;

    const int wave = tid >> 6, lane = tid & 63;
    const int row = lane & 15, kc = lane >> 4;
    const int t0 = wave * 2, t1 = t0 + 1;
    const size_t base = (size_t)bid * 128;
    const float* xp0 = x + (base + (size_t)(t0 * 16 + row)) * NN + kc * 8;
    const float* xp1 = x + (base + (size_t)(t1 * 16 + row)) * NN + kc * 8;

    // A-fragments: bf16(x), single pass (error budget validated r5/r6)
    s16x8 ah0[4], ah1[4];
#pragma unroll
    for (int kt = 0; kt < 4; ++kt) {
        const float4* p0 = (const float4*)(xp0 + kt * 32);
        const float4* p1 = (const float4*)(xp1 + kt * 32);
        float4 v00 = p0[0], v01 = p0[1], v10 = p1[0], v11 = p1[1];
        float vs0[8] = {v00.x, v00.y, v00.z, v00.w, v01.x, v01.y, v01.z, v01.w};
        float vs1[8] = {v10.x, v10.y, v10.z, v10.w, v11.x, v11.y, v11.z, v11.w};
#pragma unroll
        for (int e = 0; e < 8; ++e) {
            ah0[kt][e] = (short)f2bf_rne(vs0[e]);
            ah1[kt][e] = (short)f2bf_rne(vs1[e]);
        }
    }

    // W B-fragment vector view: wv[(nt*4+kt)*64 + lane], 16 B/lane coalesced
    const s16x8* wv = (const s16x8*)wfrag;

    // epilogue base pointers: thread (rg,cl) needs x[tile*16+rg*4+r][nt*16+cl]
    const int rg = lane >> 4, cl = lane & 15;
    const float* e0 = x + (base + (size_t)(t0 * 16 + rg * 4)) * NN + cl;
    const float* e1 = x + (base + (size_t)(t1 * 16 + rg * 4)) * NN + cl;

    float q00 = 0, q01 = 0, q02 = 0, q03 = 0;
    float q10 = 0, q11 = 0, q12 = 0, q13 = 0;
#pragma unroll 2
    for (int nt = 0; nt < 8; ++nt) {
        s16x8 b0 = wv[(nt * 4 + 0) * 64 + lane];
        s16x8 b1 = wv[(nt * 4 + 1) * 64 + lane];
        s16x8 b2 = wv[(nt * 4 + 2) * 64 + lane];
        s16x8 b3 = wv[(nt * 4 + 3) * 64 + lane];
        f32x4 c0 = {0.f, 0.f, 0.f, 0.f}, c1 = {0.f, 0.f, 0.f, 0.f};
        c0 = __builtin_amdgcn_mfma_f32_16x16x32_bf16(ah0[0], b0, c0, 0, 0, 0);
        c1 = __builtin_amdgcn_mfma_f32_16x16x32_bf16(ah1[0], b0, c1, 0, 0, 0);
        c0 = __builtin_amdgcn_mfma_f32_16x16x32_bf16(ah0[1], b1, c0, 0, 0, 0);
        c1 = __builtin_amdgcn_mfma_f32_16x16x32_bf16(ah1[1], b1, c1, 0, 0, 0);
        c0 = __builtin_amdgcn_mfma_f32_16x16x32_bf16(ah0[2], b2, c0, 0, 0, 0);
        c1 = __builtin_amdgcn_mfma_f32_16x16x32_bf16(ah1[2], b2, c1, 0, 0, 0);
        c0 = __builtin_amdgcn_mfma_f32_16x16x32_bf16(ah0[3], b3, c0, 0, 0, 0);
        c1 = __builtin_amdgcn_mfma_f32_16x16x32_bf16(ah1[3], b3, c1, 0, 0, 0);
        // D layout (m89-verified): col = lane&15, row = (lane>>4)*4 + reg
        const int nc = nt * 16;
        q00 += c0[0] * e0[0 * NN + nc];
        q01 += c0[1] * e0[1 * NN + nc];
        q02 += c0[2] * e0[2 * NN + nc];
        q03 += c0[3] * e0[3 * NN + nc];
        q10 += c1[0] * e1[0 * NN + nc];
        q11 += c1[1] * e1[1 * NN + nc];
        q12 += c1[2] * e1[2 * NN + nc];
        q13 += c1[3] * e1[3 * NN + nc];
    }
#pragma unroll
    for (int m = 1; m <= 8; m <<= 1) {
        q00 += __shfl_xor(q00, m, 64); q01 += __shfl_xor(q01, m, 64);
        q02 += __shfl_xor(q02, m, 64); q03 += __shfl_xor(q03, m, 64);
        q10 += __shfl_xor(q10, m, 64); q11 += __shfl_xor(q11, m, 64);
        q12 += __shfl_xor(q12, m, 64); q13 += __shfl_xor(q13, m, 64);
    }
    if (cl == 0) {
        float4 o0 = {q00, q01, q02, q03};
        float4 o1 = {q10, q11, q12, q13};
        *(float4*)(out + base + t0 * 16 + rg * 4) = o0;
        *(float4*)(out + base + t1 * 16 + rg * 4) = o1;
    }
}

extern "C" void kernel_launch(void* const* d_in, const int* in_sizes, int n_in,
                              void* d_out, int out_size, void* d_ws, size_t ws_size,
                              hipStream_t stream) {
    const float* x = (const float*)d_in[0];
    const float* kern = (const float*)d_in[1];
    const int* fd = (const int*)d_in[2];
    float* out = (float*)d_out;
    unsigned short* wfrag = (unsigned short*)d_ws;  // 32 KB used

    prep_w_fast<<<dim3(512), dim3(256), 0, stream>>>(kern, fd, wfrag);
    qform_nolds<<<dim3(512), dim3(256), 0, stream>>>(x, wfrag, out);
}

// Round 8
// 18.180 us; speedup vs baseline: 9.3713x; 1.1937x over previous
//
#include <hip/hip_runtime.h>

#define NB 65536
#define NN 128
#define FDIM 16
#define ODIM 64

typedef __attribute__((ext_vector_type(8))) short s16x8;
typedef __attribute__((ext_vector_type(4))) float f32x4;
typedef __attribute__((address_space(3))) void lds_void_t;
typedef const __attribute__((address_space(1))) void gbl_void_t;

__device__ __forceinline__ unsigned short f2bf_rne(float f) {
    unsigned u = __builtin_bit_cast(unsigned, f);
    u += 0x7FFFu + ((u >> 16) & 1u);
    return (unsigned short)(u >> 16);
}

// ---------------------------------------------------------------------------
// Kernel 1: W' = 0.5*S (symmetric, zero diag), bf16 B-fragment layout.
// 512 blocks x 256 threads, 8 lanes per length-64 dot.
// ---------------------------------------------------------------------------
__global__ __launch_bounds__(256) void prep_w_fast(const float* __restrict__ kern,
                                                   const int* __restrict__ fd,
                                                   unsigned short* __restrict__ wfrag) {
    int d = blockIdx.x * 32 + (threadIdx.x >> 3);  // entry: i=K idx, j=N idx
    int i = d >> 7, j = d & 127;
    int part = threadIdx.x & 7;
    int fi = fd[i], fj = fd[j];
    const float4* ap = (const float4*)(kern + (i * FDIM + fj) * ODIM + part * 8);
    const float4* bp = (const float4*)(kern + (j * FDIM + fi) * ODIM + part * 8);
    float4 a0 = ap[0], a1 = ap[1];
    float4 b0 = bp[0], b1 = bp[1];
    float s = a0.x * b0.x + a0.y * b0.y + a0.z * b0.z + a0.w * b0.w +
              a1.x * b1.x + a1.y * b1.y + a1.z * b1.z + a1.w * b1.w;
    s += __shfl_xor(s, 1, 64);
    s += __shfl_xor(s, 2, 64);
    s += __shfl_xor(s, 4, 64);
    if (part == 0) {
        float w = (i == j) ? 0.f : 0.5f * s;
        int kt = i >> 5, kc = (i >> 3) & 3, e = i & 7;
        wfrag[(((j >> 4) * 4 + kt) * 64 + kc * 16 + (j & 15)) * 8 + e] = f2bf_rne(w);
    }
}

// ---------------------------------------------------------------------------
// Kernel 2: out[b] = x_b^T W' x_b.  Verified-best structure (round 5):
//  - W staged once per block into LDS via global_load_lds (32 KB; r7 proved
//    per-wave global W reads cost +3.8 us in exposed L2 latency)
//  - single bf16 MFMA pass (error budget: absmax 0.0156 vs threshold 0.0544)
//  - epilogue reads x fp32 straight from global (L1-hot), no xlds
//  - measured at the x-stream floor: t_qform ~4.9 us vs 33.5 MB/6.3 TB/s
//    = 5.3 us (r6 replication experiment)
// ---------------------------------------------------------------------------
__global__ __launch_bounds__(256, 4) void qform(const float* __restrict__ x,
                                                const unsigned short* __restrict__ wfrag,
                                                float* __restrict__ out) {
    __shared__ __align__(16) unsigned short wlds[16384];  // 32 KB

    const int tid = threadIdx.x;
    const int bid = blockIdx.x;

    // async W stage: 32 KB, linear layout, direct-to-LDS (no VGPR round-trip)
    {
        const char* gsrc = (const char*)wfrag;
        char* ldst = (char*)wlds;
#pragma unroll
        for (int t = 0; t < 8; ++t) {
            int off = t * 4096 + tid * 16;
            __builtin_amdgcn_global_load_lds((gbl_void_t*)(gsrc + off),
                                             (lds_void_t*)(ldst + off), 16, 0, 0);
        }
    }

    const int wave = tid >> 6, lane = tid & 63;
    const int row = lane & 15, kc = lane >> 4;
    const int t0 = wave * 2, t1 = t0 + 1;
    const size_t base = (size_t)bid * 128;
    const float* xp0 = x + (base + (size_t)(t0 * 16 + row)) * NN + kc * 8;
    const float* xp1 = x + (base + (size_t)(t1 * 16 + row)) * NN + kc * 8;

    // A-fragments: bf16(x), single pass
    s16x8 ah0[4], ah1[4];
#pragma unroll
    for (int kt = 0; kt < 4; ++kt) {
        const float4* p0 = (const float4*)(xp0 + kt * 32);
        const float4* p1 = (const float4*)(xp1 + kt * 32);
        float4 v00 = p0[0], v01 = p0[1], v10 = p1[0], v11 = p1[1];
        float vs0[8] = {v00.x, v00.y, v00.z, v00.w, v01.x, v01.y, v01.z, v01.w};
        float vs1[8] = {v10.x, v10.y, v10.z, v10.w, v11.x, v11.y, v11.z, v11.w};
#pragma unroll
        for (int e = 0; e < 8; ++e) {
            ah0[kt][e] = (short)f2bf_rne(vs0[e]);
            ah1[kt][e] = (short)f2bf_rne(vs1[e]);
        }
    }
    __syncthreads();  // drains vmcnt (W stage)

    // epilogue base pointers: thread (rg,cl) needs x[tile*16+rg*4+r][nt*16+cl]
    const int rg = lane >> 4, cl = lane & 15;
    const float* e0 = x + (base + (size_t)(t0 * 16 + rg * 4)) * NN + cl;
    const float* e1 = x + (base + (size_t)(t1 * 16 + rg * 4)) * NN + cl;

    float q00 = 0, q01 = 0, q02 = 0, q03 = 0;
    float q10 = 0, q11 = 0, q12 = 0, q13 = 0;
#pragma unroll
    for (int nt = 0; nt < 8; ++nt) {
        f32x4 c0 = {0.f, 0.f, 0.f, 0.f}, c1 = {0.f, 0.f, 0.f, 0.f};
#pragma unroll
        for (int kt = 0; kt < 4; ++kt) {
            s16x8 bf = *(const s16x8*)&wlds[((nt * 4 + kt) * 64 + lane) * 8];
            c0 = __builtin_amdgcn_mfma_f32_16x16x32_bf16(ah0[kt], bf, c0, 0, 0, 0);
            c1 = __builtin_amdgcn_mfma_f32_16x16x32_bf16(ah1[kt], bf, c1, 0, 0, 0);
        }
        // D layout (m89-verified): col = lane&15, row = (lane>>4)*4 + reg
        const int nc = nt * 16;
        q00 += c0[0] * e0[0 * NN + nc];
        q01 += c0[1] * e0[1 * NN + nc];
        q02 += c0[2] * e0[2 * NN + nc];
        q03 += c0[3] * e0[3 * NN + nc];
        q10 += c1[0] * e1[0 * NN + nc];
        q11 += c1[1] * e1[1 * NN + nc];
        q12 += c1[2] * e1[2 * NN + nc];
        q13 += c1[3] * e1[3 * NN + nc];
    }
#pragma unroll
    for (int m = 1; m <= 8; m <<= 1) {
        q00 += __shfl_xor(q00, m, 64); q01 += __shfl_xor(q01, m, 64);
        q02 += __shfl_xor(q02, m, 64); q03 += __shfl_xor(q03, m, 64);
        q10 += __shfl_xor(q10, m, 64); q11 += __shfl_xor(q11, m, 64);
        q12 += __shfl_xor(q12, m, 64); q13 += __shfl_xor(q13, m, 64);
    }
    if (cl == 0) {
        float4 o0 = {q00, q01, q02, q03};
        float4 o1 = {q10, q11, q12, q13};
        *(float4*)(out + base + t0 * 16 + rg * 4) = o0;
        *(float4*)(out + base + t1 * 16 + rg * 4) = o1;
    }
}

extern "C" void kernel_launch(void* const* d_in, const int* in_sizes, int n_in,
                              void* d_out, int out_size, void* d_ws, size_t ws_size,
                              hipStream_t stream) {
    const float* x = (const float*)d_in[0];
    const float* kern = (const float*)d_in[1];
    const int* fd = (const int*)d_in[2];
    float* out = (float*)d_out;
    unsigned short* wfrag = (unsigned short*)d_ws;  // 32 KB used

    prep_w_fast<<<dim3(512), dim3(256), 0, stream>>>(kern, fd, wfrag);
    qform<<<dim3(512), dim3(256), 0, stream>>>(x, wfrag, out);
}